// Round 4
// baseline (40.553 us; speedup 1.0000x reference)
//
#include <hip/hip_runtime.h>

// Problem constants (match reference)
#define BATCH      8192
#define D_DIM      512
#define NUM_CLS    90
#define K_CENTERS  8

// Native vector type so __builtin_nontemporal_load applies (HIP float4 is a class).
typedef float v4f __attribute__((ext_vector_type(4)));

// Workspace layout:
//   ws + 0    : uint32 block-retirement counter  (zeroed by a 64 B memset node)
//   ws + 1024 : 2048 double per-block partials   (no init needed: stored, not accumulated)
//
// Tail protocol (fence-free; round-2 post-mortem showed __threadfence/ACQ_REL lower to
// per-block buffer_wbl2+inv L2 sweeps = ~85 us of serialization):
//   - partial publish: RETURNING f64 atomic_exchange (RELAXED, agent scope) into
//     partials[bid] -> executes at the device coherence point, zero contention.
//   - ordering: consume the returned value into s_waitcnt vmcnt(0), then bump the
//     retirement counter (RELAXED RMW). RMW-performed + program order = happens-before.
//   - last block: RELAXED agent-scope atomic loads (cache-bypassing) of all partials.
__global__ __launch_bounds__(256) void center_loss_fused(
    const float* __restrict__ x,
    const float* __restrict__ centers,
    const int*   __restrict__ labels,
    unsigned*    __restrict__ cnt,       // ws + 0
    double*      __restrict__ partials,  // ws + 1024
    float*       __restrict__ out)
{
    const int wave = threadIdx.x >> 6;   // 0..3
    const int lane = threadIdx.x & 63;
    const int k    = lane & 7;
    const int sub  = lane >> 3;

    const int b = blockIdx.x * 4 + wave; // one sample per wave, 0..8191

    __shared__ double s_r[4];
    __shared__ int    s_last;
    __shared__ double sm[4];

    const int label = labels[b];
    // v4f index: sub + 8*i -> float offset sub*4 + 32*i (contiguous 128B per iter across sub)
    const v4f* xr = (const v4f*)(x + (size_t)b * D_DIM) + sub;
    const v4f* cr = (const v4f*)(centers + ((size_t)label * K_CENTERS + k) * D_DIM) + sub;

    float acc = 0.0f;
#pragma unroll
    for (int i = 0; i < 16; ++i) {
        v4f xv = __builtin_nontemporal_load(xr + i * 8);  // x: zero reuse, stream it
        v4f cv = cr[i * 8];                               // centers: cached, reused
        acc = fmaf(xv.x, cv.x, acc);
        acc = fmaf(xv.y, cv.y, acc);
        acc = fmaf(xv.z, cv.z, acc);
        acc = fmaf(xv.w, cv.w, acc);
    }
    // reduce across sub (lane bits 3..5)
    acc += __shfl_xor(acc, 8);
    acc += __shfl_xor(acc, 16);
    acc += __shfl_xor(acc, 32);

    const float dk = 1.0f + acc;     // d[b,k], replicated across sub-groups
    float s1 = dk;
    float s2 = dk * dk;
    // reduce across k (lane bits 0..2)
    s1 += __shfl_xor(s1, 1);  s2 += __shfl_xor(s2, 1);
    s1 += __shfl_xor(s1, 2);  s2 += __shfl_xor(s2, 2);
    s1 += __shfl_xor(s1, 4);  s2 += __shfl_xor(s2, 4);

    const double r = (double)(s2 / s1);  // sum_k w*d = (sum d^2) / (sum d)

    if (lane == 0) s_r[wave] = r;
    __syncthreads();

    if (threadIdx.x == 0) {
        const double p = s_r[0] + s_r[1] + s_r[2] + s_r[3];
        // Zero-contention publish: returning swap at the coherence point.
        double oldv = __hip_atomic_exchange(partials + blockIdx.x, p,
                                            __ATOMIC_RELAXED, __HIP_MEMORY_SCOPE_AGENT);
        // Drain the RMW before bumping the counter. No wbl2/inv emitted.
        asm volatile("s_waitcnt vmcnt(0)" : : "v"(oldv) : "memory");
        const unsigned c = __hip_atomic_fetch_add(cnt, 1u, __ATOMIC_RELAXED,
                                                  __HIP_MEMORY_SCOPE_AGENT);
        s_last = (c == gridDim.x - 1) ? 1 : 0;
    }
    __syncthreads();

    if (s_last) {
        // Last block: fold all 2048 partials with all 256 threads (8 each, independent).
        double s = 0.0;
#pragma unroll
        for (int i = 0; i < 8; ++i) {
            s += __hip_atomic_load(partials + threadIdx.x + i * 256,
                                   __ATOMIC_RELAXED, __HIP_MEMORY_SCOPE_AGENT);
        }
        s += __shfl_xor(s, 1);
        s += __shfl_xor(s, 2);
        s += __shfl_xor(s, 4);
        s += __shfl_xor(s, 8);
        s += __shfl_xor(s, 16);
        s += __shfl_xor(s, 32);
        if (lane == 0) sm[wave] = s;
        __syncthreads();
        if (threadIdx.x == 0) {
            out[0] = (float)((sm[0] + sm[1] + sm[2] + sm[3]) / (double)BATCH);
        }
    }
}

extern "C" void kernel_launch(void* const* d_in, const int* in_sizes, int n_in,
                              void* d_out, int out_size, void* d_ws, size_t ws_size,
                              hipStream_t stream) {
    const float* x       = (const float*)d_in[0];
    const float* centers = (const float*)d_in[1];
    const int*   labels  = (const int*)d_in[2];
    float*    out      = (float*)d_out;
    unsigned* cnt      = (unsigned*)d_ws;
    double*   partials = (double*)((char*)d_ws + 1024);   // 2048 doubles = 16 KB

    // zero ONLY the retirement counter (partials are stored, not accumulated)
    hipMemsetAsync(d_ws, 0, 64, stream);

    const int nblocks = BATCH / 4;      // 2048 blocks; 4 waves/block, 1 sample/wave
    center_loss_fused<<<nblocks, 256, 0, stream>>>(x, centers, labels, cnt, partials, out);
}

// Round 5
// 25.926 us; speedup vs baseline: 1.5642x; 1.5642x over previous
//
#include <hip/hip_runtime.h>

// Problem constants (match reference)
#define BATCH      8192
#define D_DIM      512
#define NUM_CLS    90
#define K_CENTERS  8

typedef float v4f __attribute__((ext_vector_type(4)));

// Kernel 1: 512 blocks x 1024 threads; 16 waves/block, one wave (64 lanes) per sample.
// Lane layout: k = lane & 7 (which center), sub = lane >> 3 (which 64-elem chunk of D).
// Each lane: 64-elem fp32 dot via 16 float4 FMA iterations.
// Reduce over sub with shfl_xor(8,16,32); then over k with shfl_xor(1,2,4) on (d, d*d).
// Per-block: 16 wave results -> LDS -> one float partial, plain store (NO atomics:
// rounds 2-4 proved every device-scope RMW tail costs more than a dependent launch).
__global__ __launch_bounds__(1024) void center_loss_main(
    const float* __restrict__ x,
    const float* __restrict__ centers,
    const int*   __restrict__ labels,
    float*       __restrict__ partials)
{
    const int wave = threadIdx.x >> 6;   // 0..15
    const int lane = threadIdx.x & 63;
    const int k    = lane & 7;
    const int sub  = lane >> 3;

    const int b = blockIdx.x * 16 + wave;   // 0..8191

    __shared__ float s_r[16];

    const int label = labels[b];
    // v4f index: sub + 8*i -> float offset sub*4 + 32*i (contiguous 128B per iter across sub)
    const v4f* xr = (const v4f*)(x + (size_t)b * D_DIM) + sub;
    const v4f* cr = (const v4f*)(centers + ((size_t)label * K_CENTERS + k) * D_DIM) + sub;

    float acc = 0.0f;
#pragma unroll
    for (int i = 0; i < 16; ++i) {
        v4f xv = xr[i * 8];
        v4f cv = cr[i * 8];
        acc = fmaf(xv.x, cv.x, acc);
        acc = fmaf(xv.y, cv.y, acc);
        acc = fmaf(xv.z, cv.z, acc);
        acc = fmaf(xv.w, cv.w, acc);
    }
    // reduce across sub (lane bits 3..5)
    acc += __shfl_xor(acc, 8);
    acc += __shfl_xor(acc, 16);
    acc += __shfl_xor(acc, 32);

    const float dk = 1.0f + acc;     // d[b,k], replicated across sub-groups
    float s1 = dk;
    float s2 = dk * dk;
    // reduce across k (lane bits 0..2)
    s1 += __shfl_xor(s1, 1);  s2 += __shfl_xor(s2, 1);
    s1 += __shfl_xor(s1, 2);  s2 += __shfl_xor(s2, 2);
    s1 += __shfl_xor(s1, 4);  s2 += __shfl_xor(s2, 4);

    if (lane == 0) s_r[wave] = s2 / s1;   // sum_k w*d = (sum d^2) / (sum d)
    __syncthreads();

    if (threadIdx.x == 0) {
        float p = 0.0f;
#pragma unroll
        for (int i = 0; i < 16; ++i) p += s_r[i];
        partials[blockIdx.x] = p;
    }
}

// Kernel 2: single-wave reduction of 512 float partials -> float mean.
// No LDS, no __syncthreads: 64 lanes x 2 float4 loads (one latency round),
// double accumulate, 6 shuffles, one store.
__global__ __launch_bounds__(64) void center_loss_reduce(
    const float* __restrict__ partials,
    float*       __restrict__ out)
{
    const int lane = threadIdx.x;   // 0..63
    const v4f* p4 = (const v4f*)partials;

    v4f a = p4[lane];          // floats [4*lane, 4*lane+4)
    v4f b = p4[lane + 64];     // floats [256 + 4*lane, ...)

    double s = (double)a.x + (double)a.y + (double)a.z + (double)a.w
             + (double)b.x + (double)b.y + (double)b.z + (double)b.w;

    s += __shfl_xor(s, 1);
    s += __shfl_xor(s, 2);
    s += __shfl_xor(s, 4);
    s += __shfl_xor(s, 8);
    s += __shfl_xor(s, 16);
    s += __shfl_xor(s, 32);

    if (lane == 0) out[0] = (float)(s / (double)BATCH);
}

extern "C" void kernel_launch(void* const* d_in, const int* in_sizes, int n_in,
                              void* d_out, int out_size, void* d_ws, size_t ws_size,
                              hipStream_t stream) {
    const float* x       = (const float*)d_in[0];
    const float* centers = (const float*)d_in[1];
    const int*   labels  = (const int*)d_in[2];
    float* out      = (float*)d_out;
    float* partials = (float*)d_ws;     // 512 floats = 2 KB

    const int nblocks = BATCH / 16;     // 512 blocks; 16 waves/block, 1 sample/wave
    center_loss_main<<<nblocks, 1024, 0, stream>>>(x, centers, labels, partials);
    center_loss_reduce<<<1, 64, 0, stream>>>(partials, out);
}